// Round 8
// baseline (221.483 us; speedup 1.0000x reference)
//
#include <hip/hip_runtime.h>
#include <math.h>

typedef _Float16 f16;
typedef _Float16 f16x8 __attribute__((ext_vector_type(8)));
typedef float f32x4 __attribute__((ext_vector_type(4)));

#define Bn 128
#define Tn 32
#define Hn 768
#define En 4
#define Fn 3072
#define Rn 256
#define MAXT8 35
#define MAXT4 67

static constexpr size_t OUT_ELEMS  = (size_t)Rn*Tn*Hn;
static constexpr size_t SCORES_OFF = OUT_ELEMS;
static constexpr size_t ROUTE_OFF  = OUT_ELEMS + Rn;
static constexpr size_t BIDX_OFF   = OUT_ELEMS + 2*Rn;
static constexpr size_t LOSS_OFF   = OUT_ELEMS + 3*Rn;

// ws byte offsets
#define WS_WSF    0u
#define WS_ROUTE  4096u
#define WS_GRP    8192u
#define WS_X16    16384u
#define WS_W1T    (WS_X16 + 2u*Bn*Tn*Hn)
#define WS_W2T    (WS_W1T + 2u*En*Hn*Fn)
#define WS_H1     (WS_W2T + 2u*En*Fn*Hn)

#define GLOAD16(g, l) __builtin_amdgcn_global_load_lds( \
    (const __attribute__((address_space(1))) unsigned int*)(g), \
    (__attribute__((address_space(3))) unsigned int*)(l), 16, 0, 0)

__device__ __forceinline__ float fast_gelu(float v) {
  float s = v * 0.70710678118f;
  float a = fabsf(s);
  float t = 1.0f / (1.0f + 0.3275911f * a);
  float y = t*(0.254829592f + t*(-0.284496736f + t*(1.421413741f +
            t*(-1.453152027f + t*1.061405429f))));
  float er = 1.0f - y * __expf(-a*a);
  er = (s < 0.0f) ? -er : er;
  return 0.5f * v * (1.0f + er);
}

// 4-wave gate: fused x->fp16 conversion + gating logits + softmax + top2.
__global__ __launch_bounds__(256) void gate_kernel(
    const float* __restrict__ x, const float* __restrict__ Wg,
    float* __restrict__ out, float* __restrict__ wsf, int* __restrict__ route,
    f16* __restrict__ x16)
{
  const int b = blockIdx.x;
  const int tid = threadIdx.x;
  const int w = tid >> 6, l = tid & 63;
  __shared__ float pacc[4][4];
  float a0=0.f, a1=0.f, a2=0.f, a3=0.f;
  const float* xb = x   + (size_t)b*Tn*Hn + (size_t)(w*8)*Hn;
  f16*         xh = x16 + (size_t)b*Tn*Hn + (size_t)(w*8)*Hn;
  #pragma unroll
  for (int k = 0; k < 12; ++k) {
    const int h = l + 64*k;
    const float w0 = Wg[0*Hn+h], w1 = Wg[1*Hn+h], w2 = Wg[2*Hn+h], w3 = Wg[3*Hn+h];
    #pragma unroll
    for (int t = 0; t < 8; ++t) {
      float v = xb[t*Hn + h];
      xh[t*Hn + h] = (f16)v;
      a0 += v*w0; a1 += v*w1; a2 += v*w2; a3 += v*w3;
    }
  }
  #pragma unroll
  for (int o = 32; o > 0; o >>= 1) {
    a0 += __shfl_down(a0,o); a1 += __shfl_down(a1,o);
    a2 += __shfl_down(a2,o); a3 += __shfl_down(a3,o);
  }
  if (l == 0) { pacc[w][0]=a0; pacc[w][1]=a1; pacc[w][2]=a2; pacc[w][3]=a3; }
  __syncthreads();
  if (tid == 0) {
    float lg[4];
    #pragma unroll
    for (int e = 0; e < 4; ++e)
      lg[e] = (pacc[0][e]+pacc[1][e]+pacc[2][e]+pacc[3][e]) * (1.0f/Tn);
    float m = fmaxf(fmaxf(lg[0],lg[1]), fmaxf(lg[2],lg[3]));
    float p[4]; float s = 0.f;
    #pragma unroll
    for (int e = 0; e < 4; ++e) { p[e] = expf(lg[e]-m); s += p[e]; }
    float inv = 1.f/s;
    #pragma unroll
    for (int e = 0; e < 4; ++e) { p[e] *= inv; wsf[b*4+e] = p[e]; }
    int i1 = 0;
    #pragma unroll
    for (int e = 1; e < 4; ++e) if (p[e] > p[i1]) i1 = e;
    int i2 = (i1 == 0) ? 1 : 0;
    #pragma unroll
    for (int e = 0; e < 4; ++e) if (e != i1 && p[e] > p[i2]) i2 = e;
    int idx[2] = {i1, i2};
    #pragma unroll
    for (int k = 0; k < 2; ++k) {
      int r = 2*b + k;
      float pv = p[idx[k]];
      wsf[512 + r] = pv;
      route[r] = idx[k];
      out[SCORES_OFF + r] = pv;
      out[ROUTE_OFF  + r] = (float)idx[k];
      out[BIDX_OFF   + r] = (float)r;
    }
  }
}

__global__ __launch_bounds__(64) void loss_kernel(
    const float* __restrict__ wsf, float* __restrict__ out)
{
  const int l = threadIdx.x;
  float i0=0.f,i1=0.f,i2=0.f,i3=0.f;
  for (int b = l; b < Bn; b += 64) {
    i0 += wsf[b*4+0]; i1 += wsf[b*4+1]; i2 += wsf[b*4+2]; i3 += wsf[b*4+3];
  }
  #pragma unroll
  for (int o = 32; o > 0; o >>= 1) {
    i0 += __shfl_down(i0,o); i1 += __shfl_down(i1,o);
    i2 += __shfl_down(i2,o); i3 += __shfl_down(i3,o);
  }
  if (l == 0) {
    float mean = 0.25f*(i0+i1+i2+i3);
    float d0=i0-mean, d1=i1-mean, d2=i2-mean, d3=i3-mean;
    float var = (d0*d0+d1*d1+d2*d2+d3*d3) * (1.f/3.f);
    out[LOSS_OFF] = var / (mean*mean);
  }
}

// grp: [0]=nt8, [1]=nt4; tiles8 at [8+3i] (e,bstart,nb<=8); tiles4 at [128+3i]
// (e,bstart,nb<=4); blist at [384..639]
__global__ __launch_bounds__(64) void group_kernel(
    const int* __restrict__ route, int* __restrict__ grp)
{
  const int l = threadIdx.x;
  int cnt = 0;
  if (l < 4) { for (int r = 0; r < Rn; ++r) cnt += (route[r] == l); }
  int c0 = __shfl(cnt, 0), c1 = __shfl(cnt, 1), c2 = __shfl(cnt, 2), c3 = __shfl(cnt, 3);
  int off = (l >= 1 ? c0 : 0) + (l >= 2 ? c1 : 0) + (l >= 3 ? c2 : 0);
  if (l < 4) {
    int p = off;
    for (int r = 0; r < Rn; ++r) if (route[r] == l) grp[384 + p++] = r;
  }
  if (l == 0) {
    int cs[4] = {c0, c1, c2, c3};
    int os[4] = {0, c0, c0+c1, c0+c1+c2};
    int nt8 = 0, nt4 = 0;
    for (int e = 0; e < 4; ++e) {
      for (int s = 0; s < cs[e]; s += 8) {
        int nb = cs[e] - s; if (nb > 8) nb = 8;
        grp[8+nt8*3+0] = e; grp[8+nt8*3+1] = os[e]+s; grp[8+nt8*3+2] = nb;
        ++nt8;
      }
      for (int s = 0; s < cs[e]; s += 4) {
        int nb = cs[e] - s; if (nb > 4) nb = 4;
        grp[128+nt4*3+0] = e; grp[128+nt4*3+1] = os[e]+s; grp[128+nt4*3+2] = nb;
        ++nt4;
      }
    }
    grp[0] = nt8;
    grp[1] = nt4;
  }
}

// src [E][R][C] fp32 -> dst [E][C][R] fp16.  grid (C/64, R/64, E), block 256.
__global__ __launch_bounds__(256) void transcvt_kernel(
    const float* __restrict__ src, f16* __restrict__ dst, int R, int C)
{
  __shared__ f16 t[64][74];
  const int e  = blockIdx.z;
  const int r0 = blockIdx.y*64, c0 = blockIdx.x*64;
  const float* s = src + (size_t)e*R*C;
  f16* d = dst + (size_t)e*R*C;
  const int tid = threadIdx.x;
  const int i  = tid >> 2;
  const int j0 = (tid & 3) * 16;
  #pragma unroll
  for (int q = 0; q < 16; q += 4) {
    float4 v = *(const float4*)(s + (size_t)(r0+i)*C + c0 + j0 + q);
    t[i][j0+q+0]=(f16)v.x; t[i][j0+q+1]=(f16)v.y; t[i][j0+q+2]=(f16)v.z; t[i][j0+q+3]=(f16)v.w;
  }
  __syncthreads();
  f16 o[16];
  #pragma unroll
  for (int q = 0; q < 16; ++q) o[q] = t[j0+q][i];
  *(uint4*)(d + (size_t)(c0+i)*R + r0 + j0)     = *(uint4*)&o[0];
  *(uint4*)(d + (size_t)(c0+i)*R + r0 + j0 + 8) = *(uint4*)&o[8];
}

// Grouped GEMM, 8 waves (512 thr), BK=32, QUAD-buffer depth-3 prefetch,
// one barrier + counted vmcnt per K-step, setprio MFMA clusters.
// g1: BM=256 BN=256 wave-tile 128x64 (MI=8). g2: BM=128 BN=128 wave 32x64 (MI=2).
template<int KD, int ND, int BN, int MI, int NWY, bool G1>
__global__ __launch_bounds__(512, G1 ? 2 : 4) void gemm_kernel(
    const f16* __restrict__ A16, const f16* __restrict__ B16,
    const float* __restrict__ bias, f16* __restrict__ oh,
    float* __restrict__ of, const int* __restrict__ grp,
    const float* __restrict__ wsf)
{
  constexpr int NWM  = 8 / NWY;
  constexpr int BM   = NWM * MI * 16;
  constexpr int NY   = ND / BN;
  constexpr int BI_A = BM / 128;
  constexpr int BI_B = BN / 128;
  constexpr int NLD  = BI_A + BI_B;
  constexpr int BUFSZ = (BM + BN) * 64;
  constexpr int C0   = (MI < 4) ? MI : 4;
  constexpr int TOFF = G1 ? 8 : 128;

  const int ntiles = grp[G1 ? 0 : 1];
  const int tix = blockIdx.x / NY;
  const int ny  = blockIdx.x % NY;
  if (tix >= ntiles) return;
  const int e      = grp[TOFF+tix*3+0];
  const int bstart = grp[TOFF+tix*3+1];
  const int nb     = grp[TOFF+tix*3+2];
  const int n0     = ny * BN;
  const int tid    = threadIdx.x;
  const int lane   = tid & 63;
  const int w      = tid >> 6;

  extern __shared__ __align__(16) char smem[];

  // ---- staging sources (pre-swizzled unit: (l&3) ^ ((l>>3)&3)) ----
  const int srow  = lane >> 2;
  const int sunit = (lane & 3) ^ ((lane >> 3) & 3);
  const f16* asrc[BI_A];
  #pragma unroll
  for (int i = 0; i < BI_A; ++i) {
    int row = (w*BI_A + i)*16 + srow;
    int slot = row >> 5; if (slot >= nb) slot = nb - 1;
    int beam = grp[384 + bstart + slot];
    size_t rbase = G1 ? ((size_t)(beam>>1)*Tn + (row&31)) * (size_t)KD
                      : ((size_t)beam*Tn + (row&31)) * (size_t)KD;
    asrc[i] = A16 + rbase + sunit*8;
  }
  const f16* bsrc[BI_B];
  #pragma unroll
  for (int i = 0; i < BI_B; ++i) {
    int row = (w*BI_B + i)*16 + srow;
    bsrc[i] = B16 + (size_t)e*ND*KD + (size_t)(n0 + row)*KD + sunit*8;
  }

  // ---- fragment geometry ----
  const int wm = w / NWY, wn = w % NWY;
  const int lr = lane & 15, lk = lane >> 4;
  const int rowA0 = wm*(MI*16);
  const int rowB0 = wn*64;
  const int ub = (lk ^ ((lr >> 1) & 3)) << 4;

  f32x4 acc[MI][4];
  #pragma unroll
  for (int i=0;i<MI;++i)
    #pragma unroll
    for (int j=0;j<4;++j) acc[i][j] = (f32x4){0.f,0.f,0.f,0.f};

  constexpr int NT = KD/32;
  static_assert(NT % 4 == 0 && NT >= 8, "NT must be multiple of 4, >=8");

  auto STAGE = [&](int bsel, int kt2) {
    char* Ad = smem + bsel*BUFSZ + (w*BI_A)*1024;
    #pragma unroll
    for (int i = 0; i < BI_A; ++i) GLOAD16(asrc[i] + kt2*32, Ad + i*1024);
    char* Bd = smem + bsel*BUFSZ + BM*64 + (w*BI_B)*1024;
    #pragma unroll
    for (int i = 0; i < BI_B; ++i) GLOAD16(bsrc[i] + kt2*32, Bd + i*1024);
  };

#define STEP(BUFI, SBI, KTS, VMC, DOST) do { \
    asm volatile("s_waitcnt vmcnt(%0)" :: "i"(VMC) : "memory"); \
    __builtin_amdgcn_sched_barrier(0); \
    __builtin_amdgcn_s_barrier(); \
    __builtin_amdgcn_sched_barrier(0); \
    { \
      const char* Ab = smem + (BUFI)*BUFSZ; \
      const char* Bb = Ab + BM*64; \
      f16x8 af0[C0], bf[4]; \
      _Pragma("unroll") \
      for (int ni=0;ni<4;++ni) \
        bf[ni] = *(const f16x8*)(Bb + (rowB0 + ni*16 + lr)*64 + ub); \
      _Pragma("unroll") \
      for (int mi=0;mi<C0;++mi) \
        af0[mi] = *(const f16x8*)(Ab + (rowA0 + mi*16 + lr)*64 + ub); \
      if (DOST) STAGE(SBI, KTS); \
      __builtin_amdgcn_s_setprio(1); \
      _Pragma("unroll") \
      for (int mi=0;mi<C0;++mi) \
        _Pragma("unroll") \
        for (int ni=0;ni<4;++ni) \
          acc[mi][ni] = __builtin_amdgcn_mfma_f32_16x16x32_f16(af0[mi], bf[ni], acc[mi][ni], 0, 0, 0); \
      __builtin_amdgcn_s_setprio(0); \
      if constexpr (MI == 8) { \
        f16x8 af1[4]; \
        _Pragma("unroll") \
        for (int mi=0;mi<4;++mi) \
          af1[mi] = *(const f16x8*)(Ab + (rowA0 + (mi+4)*16 + lr)*64 + ub); \
        __builtin_amdgcn_s_setprio(1); \
        _Pragma("unroll") \
        for (int mi=0;mi<4;++mi) \
          _Pragma("unroll") \
          for (int ni=0;ni<4;++ni) \
            acc[mi+4][ni] = __builtin_amdgcn_mfma_f32_16x16x32_f16(af1[mi], bf[ni], acc[mi+4][ni], 0, 0, 0); \
        __builtin_amdgcn_s_setprio(0); \
      } \
    } \
  } while (0)

  // prologue: depth-3
  STAGE(0, 0);
  STAGE(1, 1);
  STAGE(2, 2);

  for (int kt = 0; kt + 8 <= NT; kt += 4) {
    STEP(0, 3, kt+3, 2*NLD, true);
    STEP(1, 0, kt+4, 2*NLD, true);
    STEP(2, 1, kt+5, 2*NLD, true);
    STEP(3, 2, kt+6, 2*NLD, true);
  }
  // tail: steps NT-4..NT-1 (bufs 0,1,2,3)
  STEP(0, 3, NT-1, 2*NLD, true);
  STEP(1, 0, 0,    2*NLD, false);
  STEP(2, 0, 0,    NLD,   false);
  STEP(3, 0, 0,    0,     false);
#undef STEP

  __syncthreads();   // bufs dead; cst region reuse

  // ---- epilogue: BM/128 passes of 128 rows through 64KB swizzled LDS ----
  const int nvalid = nb * Tn;
  char* cst = smem;
  constexpr int EPH = BM / 128;
  float bvals[4];
  if (G1) {
    #pragma unroll
    for (int ni=0;ni<4;++ni) bvals[ni] = bias[e*ND + n0 + rowB0 + ni*16 + lr];
  }

  #pragma unroll
  for (int h = 0; h < EPH; ++h) {
    #pragma unroll
    for (int mi=0;mi<MI;++mi){
      #pragma unroll
      for (int j=0;j<4;++j){
        const int mglob = rowA0 + mi*16 + (lane>>4)*4 + j;
        if ((mglob >> 7) == h) {
          const int m = mglob & 127;
          const int m7 = m & 7;
          #pragma unroll
          for (int ni=0;ni<4;++ni){
            const int n = rowB0 + ni*16 + lr;
            if (G1) {
              float v = acc[mi][ni][j] + bvals[ni];
              *(f16*)(cst + m*512 + (((n>>3)^m7)<<4) + (n&7)*2) = (f16)fast_gelu(v);
            } else {
              *(float*)(cst + m*512 + (((n>>2)^m7)<<4) + (n&3)*4) = acc[mi][ni][j];
            }
          }
        }
      }
    }
    __syncthreads();
    const int u  = tid & 31;
    const int tr = tid >> 5;
    float4 b4;
    if (!G1) b4 = *(const float4*)(bias + e*ND + n0 + u*4);
    #pragma unroll
    for (int it = 0; it < 8; ++it) {
      const int rl = it*16 + tr;
      const int r  = h*128 + rl;
      if (r < nvalid) {
        const int beam = grp[384 + bstart + (r>>5)];
        if (G1) {
          uint4 v = *(const uint4*)(cst + rl*512 + (((u&24)|((u&7)^(rl&7)))<<4));
          *(uint4*)(oh + ((size_t)beam*Tn + (r&31))*(size_t)ND + n0 + u*8) = v;
        } else {
          const float sc = wsf[512 + beam];
          float4 v = *(const float4*)(cst + rl*512 + (((u&24)|((u&7)^(rl&7)))<<4));
          v.x = (v.x + b4.x)*sc; v.y = (v.y + b4.y)*sc;
          v.z = (v.z + b4.z)*sc; v.w = (v.w + b4.w)*sc;
          *(float4*)(of + ((size_t)beam*Tn + (r&31))*(size_t)Hn + n0 + u*4) = v;
        }
      }
    }
    if (h + 1 < EPH) __syncthreads();
  }
}

extern "C" void kernel_launch(void* const* d_in, const int* in_sizes, int n_in,
                              void* d_out, int out_size, void* d_ws, size_t ws_size,
                              hipStream_t stream)
{
  const float* x  = (const float*)d_in[0];
  const float* Wg = (const float*)d_in[1];
  const float* W1 = (const float*)d_in[2];
  const float* b1 = (const float*)d_in[3];
  const float* W2 = (const float*)d_in[4];
  const float* b2 = (const float*)d_in[5];
  float* out = (float*)d_out;
  char* ws = (char*)d_ws;
  float* wsf  = (float*)(ws + WS_WSF);
  int*   route= (int*)(ws + WS_ROUTE);
  int*   grp  = (int*)(ws + WS_GRP);
  f16*   x16  = (f16*)(ws + WS_X16);
  f16*   w1t  = (f16*)(ws + WS_W1T);
  f16*   w2t  = (f16*)(ws + WS_W2T);
  f16*   h1   = (f16*)(ws + WS_H1);

  gate_kernel<<<Bn, 256, 0, stream>>>(x, Wg, out, wsf, route, x16);
  group_kernel<<<1, 64, 0, stream>>>(route, grp);
  loss_kernel<<<1, 64, 0, stream>>>(wsf, out);
  transcvt_kernel<<<dim3(48,12,4), 256, 0, stream>>>(W1, w1t, Hn, Fn);
  transcvt_kernel<<<dim3(12,48,4), 256, 0, stream>>>(W2, w2t, Fn, Hn);

  auto g1 = gemm_kernel<Hn, Fn, 256, 8, 4, true>;    // BM256/BN256, LDS 128KB
  auto g2 = gemm_kernel<Fn, Hn, 128, 2, 2, false>;   // BM128/BN128, LDS 64KB
  const int sm1 = 4 * (256 + 256) * 64;   // 131072
  const int sm2 = 4 * (128 + 128) * 64;   // 65536
  hipFuncSetAttribute((const void*)g1, hipFuncAttributeMaxDynamicSharedMemorySize, sm1);
  hipFuncSetAttribute((const void*)g2, hipFuncAttributeMaxDynamicSharedMemorySize, sm2);
  g1<<<MAXT8*12, 512, sm1, stream>>>(x16, w1t, b1, h1, nullptr, grp, wsf);
  g2<<<MAXT4*6,  512, sm2, stream>>>(h1, w2t, b2, nullptr, out, grp, wsf);
}